// Round 1
// 829.383 us; speedup vs baseline: 1.0076x; 1.0076x over previous
//
#include <hip/hip_runtime.h>

#define B_SZ   16384
#define F_N    26
#define V_N    100000
#define D_N    64
#define H1_N   512
#define H2_N   256
#define IN_DIM 1989
#define KPAD   2048

typedef _Float16 half8_t __attribute__((ext_vector_type(8)));
typedef _Float16 half4_t __attribute__((ext_vector_type(4)));
typedef float    floatx4 __attribute__((ext_vector_type(4)));

#define MFMA16(a, b, c) __builtin_amdgcn_mfma_f32_16x16x32_f16((a), (b), (c), 0, 0, 0)

__device__ __forceinline__ void load_lds16(const void* g, void* l) {
    __builtin_amdgcn_global_load_lds(
        (const __attribute__((address_space(1))) unsigned int*)g,
        (__attribute__((address_space(3))) unsigned int*)l,
        16, 0, 0);
}

// ---------------------------------------------------------------------------
// Weight prep: WT[n][k] = fp16(W[k][n]), zero pad k in [K, Kpad)
// Flipped mapping vs previous version: consecutive threads -> consecutive n,
// so the W read is coalesced (was stride-2KB, 16x fetch amplification).
// The 2B scattered writes merge in L2 (every line of WT is fully written).
// ---------------------------------------------------------------------------
__global__ __launch_bounds__(256) void prep_w(const float* __restrict__ W,
                                              _Float16* __restrict__ WT,
                                              int K, int N, int Kpad) {
    int t = blockIdx.x * 256 + threadIdx.x;
    if (t >= N * Kpad) return;
    int k = t / N;            // N is a power of two here (512 / 256)
    int n = t - k * N;
    WT[(size_t)n * Kpad + k] = (k < K) ? (_Float16)W[(size_t)k * N + n] : (_Float16)0.f;
}

// ---------------------------------------------------------------------------
// Gather + interactions. 4 samples per block (one per wave).
// joint row: [0,1664) = emb flat (fp16), [1664,1989) = upper-tri gram, pad->0
// Gather loop split into (a) issue all independent loads to regs, (b) convert
// + store — gives ~7 outstanding loads/thread instead of ~1.
// ---------------------------------------------------------------------------
#define EMB_STRIDE 72                      // 64 + 8 pad halfs (breaks bank alias)
#define EMB_PER_SAMPLE (32 * EMB_STRIDE)   // 32 rows (26 data + 6 zero)

__global__ __launch_bounds__(256) void gather_interact(
        const int* __restrict__ idx,
        const float* __restrict__ tables,
        _Float16* __restrict__ joint) {
    __shared__ __align__(16) _Float16 embh[4 * EMB_PER_SAMPLE];
    __shared__ int sidx[4 * F_N];
    const int tid = threadIdx.x;
    const int b0  = blockIdx.x * 4;

    if (tid < 4 * F_N) sidx[tid] = idx[(size_t)b0 * F_N + tid];

    // zero MFMA pad rows 26..31 (k in [0,64))
    for (int z = tid; z < 4 * 6 * 16; z += 256) {
        int s = z / 96, rem = z % 96;
        int f = F_N + rem / 16, d4 = (rem % 16) * 4;
        half4_t zz; zz[0] = 0; zz[1] = 0; zz[2] = 0; zz[3] = 0;
        *(half4_t*)(embh + s * EMB_PER_SAMPLE + f * EMB_STRIDE + d4) = zz;
    }
    __syncthreads();

    // gather: 4 samples x 26 rows x 16 float4 chunks = 1664 chunks
    float4 v[7];
    #pragma unroll
    for (int i = 0; i < 7; ++i) {
        int c = tid + i * 256;
        if (c < 4 * F_N * 16) {
            int s = c / 416, rem = c - s * 416;
            int f = rem >> 4, d4 = (rem & 15) * 4;
            v[i] = *(const float4*)(tables +
                     ((size_t)f * V_N + sidx[s * F_N + f]) * D_N + d4);
        }
    }
    #pragma unroll
    for (int i = 0; i < 7; ++i) {
        int c = tid + i * 256;
        if (c < 4 * F_N * 16) {
            int s = c / 416, rem = c - s * 416;
            int f = rem >> 4, d4 = (rem & 15) * 4;
            half4_t h;
            h[0] = (_Float16)v[i].x; h[1] = (_Float16)v[i].y;
            h[2] = (_Float16)v[i].z; h[3] = (_Float16)v[i].w;
            *(half4_t*)(embh + s * EMB_PER_SAMPLE + f * EMB_STRIDE + d4) = h;
            *(half4_t*)(joint + (size_t)(b0 + s) * KPAD + f * D_N + d4) = h;
        }
    }
    // zero joint K-pad
    for (int q = tid; q < 4 * (KPAD - IN_DIM); q += 256) {
        int s = q / (KPAD - IN_DIM), p = q % (KPAD - IN_DIM);
        joint[(size_t)(b0 + s) * KPAD + IN_DIM + p] = (_Float16)0.f;
    }
    __syncthreads();

    // per-wave gram via MFMA: gram = E (32x64) x E^T (64x32), E^T B-frag == E A-frag
    const int wave = tid >> 6, lane = tid & 63;
    const _Float16* eb = embh + wave * EMB_PER_SAMPLE;
    const int fr = lane & 15;
    const int fk = (lane >> 4) * 8;
    floatx4 a00 = {0.f, 0.f, 0.f, 0.f};
    floatx4 a01 = {0.f, 0.f, 0.f, 0.f};
    floatx4 a11 = {0.f, 0.f, 0.f, 0.f};
    #pragma unroll
    for (int k0 = 0; k0 < 64; k0 += 32) {
        half8_t f0 = *(const half8_t*)(eb + fr * EMB_STRIDE + k0 + fk);
        half8_t f1 = *(const half8_t*)(eb + (16 + fr) * EMB_STRIDE + k0 + fk);
        a00 = MFMA16(f0, f0, a00);   // m in [0,16),  n in [0,16)
        a01 = MFMA16(f0, f1, a01);   // m in [0,16),  n in [16,32)
        a11 = MFMA16(f1, f1, a11);   // m in [16,32), n in [16,32)
    }
    // extract upper triangle: D[row=(lane>>4)*4+r][col=lane&15]
    _Float16* jrow = joint + (size_t)(b0 + wave) * KPAD + F_N * D_N;
    #pragma unroll
    for (int r = 0; r < 4; ++r) {
        int mb = (lane >> 4) * 4 + r;
        {   // tile (0,0): m=mb, n=fr
            int m = mb, n = fr;
            if (m < n) jrow[(m * (51 - m)) / 2 + n - m - 1] = (_Float16)a00[r];
        }
        {   // tile (0,1): m=mb, n=16+fr
            int m = mb, n = 16 + fr;
            if (n < F_N) jrow[(m * (51 - m)) / 2 + n - m - 1] = (_Float16)a01[r];
        }
        {   // tile (1,1): m=16+mb, n=16+fr
            int m = 16 + mb, n = 16 + fr;
            if (m < n && n < F_N) jrow[(m * (51 - m)) / 2 + n - m - 1] = (_Float16)a11[r];
        }
    }
}

// ---------------------------------------------------------------------------
// C = relu(A @ Bt^T + bias), fp16 in/out, fp32 accumulate.
// 128x128 tile, BK=32, 256 threads (4 waves, each 64x64), m97 structure.
// NEW: XCD-aware chunked blockIdx swizzle (T1) — the 4 bn-siblings sharing an
// A-tile land on the same XCD L2 instead of being round-robined across 8.
// ---------------------------------------------------------------------------
__global__ __launch_bounds__(256) void gemm_bt(
        const _Float16* __restrict__ A, int lda,
        const _Float16* __restrict__ Bt, int ldb,
        const float* __restrict__ bias,
        _Float16* __restrict__ C, int ldc,
        int K, int nblocks) {
    __shared__ __align__(16) _Float16 As[128 * 32];
    __shared__ __align__(16) _Float16 Bs[128 * 32];
    const int tid  = threadIdx.x;
    const int wave = tid >> 6;
    const int lane = tid & 63;
    int bid = blockIdx.x;
    if ((gridDim.x & 7) == 0) {             // bijective chunked XCD swizzle
        const int cpx = gridDim.x >> 3;
        bid = (bid & 7) * cpx + (bid >> 3);
    }
    const int bm = bid / nblocks;
    const int bn = bid % nblocks;
    const int m0 = bm * 128, n0 = bn * 128;

    // staging: 512 chunks of 16B per tile; chunk c -> row c>>2, k-part (c&3)*8
    const int c0 = tid, c1 = tid + 256;
    const _Float16* ag0 = A  + (size_t)(m0 + (c0 >> 2)) * lda + (c0 & 3) * 8;
    const _Float16* ag1 = A  + (size_t)(m0 + (c1 >> 2)) * lda + (c1 & 3) * 8;
    const _Float16* bg0 = Bt + (size_t)(n0 + (c0 >> 2)) * ldb + (c0 & 3) * 8;
    const _Float16* bg1 = Bt + (size_t)(n0 + (c1 >> 2)) * ldb + (c1 & 3) * 8;
    char* asd0 = (char*)As + wave * 1024;
    char* asd1 = (char*)As + 4096 + wave * 1024;
    char* bsd0 = (char*)Bs + wave * 1024;
    char* bsd1 = (char*)Bs + 4096 + wave * 1024;

    floatx4 acc[4][4];
    #pragma unroll
    for (int i = 0; i < 4; ++i)
        #pragma unroll
        for (int j = 0; j < 4; ++j) acc[i][j] = (floatx4){0.f, 0.f, 0.f, 0.f};

    const int wm = (wave >> 1) * 64;
    const int wn = (wave & 1) * 64;
    const int fr = lane & 15;
    const int fk = (lane >> 4) * 8;

    for (int k0 = 0; k0 < K; k0 += 32) {
        load_lds16(ag0 + k0, asd0);
        load_lds16(ag1 + k0, asd1);
        load_lds16(bg0 + k0, bsd0);
        load_lds16(bg1 + k0, bsd1);
        __syncthreads();
        half8_t af[4], bf[4];
        #pragma unroll
        for (int i = 0; i < 4; ++i)
            af[i] = *(const half8_t*)(As + (wm + i * 16 + fr) * 32 + fk);
        #pragma unroll
        for (int j = 0; j < 4; ++j)
            bf[j] = *(const half8_t*)(Bs + (wn + j * 16 + fr) * 32 + fk);
        #pragma unroll
        for (int i = 0; i < 4; ++i)
            #pragma unroll
            for (int j = 0; j < 4; ++j)
                acc[i][j] = MFMA16(af[i], bf[j], acc[i][j]);
        __syncthreads();
    }

    const int colb = n0 + wn + fr;
    const int rowb = m0 + wm + (lane >> 4) * 4;
    #pragma unroll
    for (int j = 0; j < 4; ++j) {
        const int c = colb + j * 16;
        const float bv = bias[c];
        #pragma unroll
        for (int i = 0; i < 4; ++i)
            #pragma unroll
            for (int r = 0; r < 4; ++r) {
                float v = acc[i][j][r] + bv;
                v = fmaxf(v, 0.f);
                C[(size_t)(rowb + i * 16 + r) * ldc + c] = (_Float16)v;
            }
    }
}

// ---------------------------------------------------------------------------
// Fused tail: out = relu(h1 @ W2 + b2) @ W3 + b3.
// Block = 128 rows x all 256 cols, 512 threads (8 waves, 2M x 4N, each 64x64).
// h2 never leaves registers (fp32) -> saves the 8.4MB x2 h2 round-trip, one
// launch, and improves accuracy slightly.
// ---------------------------------------------------------------------------
__global__ __launch_bounds__(512) void fused_tail(
        const _Float16* __restrict__ h1, const _Float16* __restrict__ W2T,
        const float* __restrict__ b2, const float* __restrict__ W3,
        const float* __restrict__ b3, float* __restrict__ out) {
    __shared__ __align__(16) _Float16 As[128 * 32];   // 8 KB
    __shared__ __align__(16) _Float16 Bs[256 * 32];   // 16 KB
    __shared__ float red[4][128];                     // cross-wave partials
    const int tid  = threadIdx.x;
    const int wave = tid >> 6;
    const int lane = tid & 63;
    const int m0 = blockIdx.x * 128;

    // staging: A = 512 chunks (1/thread), B = 1024 chunks (2/thread)
    const int ca = tid, cb0 = tid, cb1 = tid + 512;
    const _Float16* ag  = h1  + (size_t)(m0 + (ca >> 2)) * H1_N + (ca & 3) * 8;
    const _Float16* bg0 = W2T + (size_t)(cb0 >> 2) * H1_N + (cb0 & 3) * 8;
    const _Float16* bg1 = W2T + (size_t)(cb1 >> 2) * H1_N + (cb1 & 3) * 8;
    char* asd  = (char*)As + wave * 1024;
    char* bsd0 = (char*)Bs + wave * 1024;
    char* bsd1 = (char*)Bs + 8192 + wave * 1024;

    floatx4 acc[4][4];
    #pragma unroll
    for (int i = 0; i < 4; ++i)
        #pragma unroll
        for (int j = 0; j < 4; ++j) acc[i][j] = (floatx4){0.f, 0.f, 0.f, 0.f};

    const int wm = (wave >> 2) * 64;          // 0 / 64
    const int wn = (wave & 3) * 64;           // 0 / 64 / 128 / 192
    const int fr = lane & 15;
    const int fk = (lane >> 4) * 8;

    for (int k0 = 0; k0 < H1_N; k0 += 32) {
        load_lds16(ag  + k0, asd);
        load_lds16(bg0 + k0, bsd0);
        load_lds16(bg1 + k0, bsd1);
        __syncthreads();
        half8_t af[4], bf[4];
        #pragma unroll
        for (int i = 0; i < 4; ++i)
            af[i] = *(const half8_t*)(As + (wm + i * 16 + fr) * 32 + fk);
        #pragma unroll
        for (int j = 0; j < 4; ++j)
            bf[j] = *(const half8_t*)(Bs + (wn + j * 16 + fr) * 32 + fk);
        #pragma unroll
        for (int i = 0; i < 4; ++i)
            #pragma unroll
            for (int j = 0; j < 4; ++j)
                acc[i][j] = MFMA16(af[i], bf[j], acc[i][j]);
        __syncthreads();
    }

    // epilogue: h2 = relu(acc + b2[col]); p = h2 . W3 over this wave's 64 cols
    float b2v[4], w3v[4];
    #pragma unroll
    for (int j = 0; j < 4; ++j) {
        const int c = wn + j * 16 + fr;
        b2v[j] = b2[c];
        w3v[j] = W3[c];
    }
    #pragma unroll
    for (int i = 0; i < 4; ++i)
        #pragma unroll
        for (int r = 0; r < 4; ++r) {
            float p = 0.f;
            #pragma unroll
            for (int j = 0; j < 4; ++j) {
                float h = acc[i][j][r] + b2v[j];
                h = fmaxf(h, 0.f);
                p += h * w3v[j];
            }
            p += __shfl_xor(p, 1, 16);
            p += __shfl_xor(p, 2, 16);
            p += __shfl_xor(p, 4, 16);
            p += __shfl_xor(p, 8, 16);
            if (fr == 0)
                red[wave & 3][wm + i * 16 + (lane >> 4) * 4 + r] = p;
        }
    __syncthreads();
    if (tid < 128) {
        float s = red[0][tid] + red[1][tid] + red[2][tid] + red[3][tid] + b3[0];
        out[m0 + tid] = s;
    }
}

// ---------------------------------------------------------------------------
extern "C" void kernel_launch(void* const* d_in, const int* in_sizes, int n_in,
                              void* d_out, int out_size, void* d_ws, size_t ws_size,
                              hipStream_t stream) {
    const int*   idx    = (const int*)d_in[0];
    const float* tables = (const float*)d_in[1];
    const float* W1     = (const float*)d_in[2];
    const float* b1     = (const float*)d_in[3];
    const float* W2     = (const float*)d_in[4];
    const float* b2     = (const float*)d_in[5];
    const float* W3     = (const float*)d_in[6];
    const float* b3     = (const float*)d_in[7];
    float* out = (float*)d_out;

    char* ws = (char*)d_ws;
    // joint: 16384*2048*2      =  67,108,864
    // W1T:   512*2048*2        =   2,097,152
    // h1:    16384*512*2       =  16,777,216
    // W2T:   256*512*2         =     262,144   total ~86.2 MB
    _Float16* joint = (_Float16*)(ws);
    _Float16* W1T   = (_Float16*)(ws + 67108864);
    _Float16* h1    = (_Float16*)(ws + 69206016);
    _Float16* W2T   = (_Float16*)(ws + 85983232);

    prep_w<<<(H1_N * KPAD + 255) / 256, 256, 0, stream>>>(W1, W1T, IN_DIM, H1_N, KPAD);
    prep_w<<<(H2_N * H1_N + 255) / 256, 256, 0, stream>>>(W2, W2T, H1_N, H2_N, H1_N);
    gather_interact<<<B_SZ / 4, 256, 0, stream>>>(idx, tables, joint);
    gemm_bt<<<(B_SZ / 128) * (H1_N / 128), 256, 0, stream>>>(
        joint, KPAD, W1T, KPAD, b1, h1, H1_N, KPAD, H1_N / 128);
    fused_tail<<<B_SZ / 128, 512, 0, stream>>>(h1, W2T, b2, W3, b3, out);
}

// Round 2
// 824.767 us; speedup vs baseline: 1.0133x; 1.0056x over previous
//
#include <hip/hip_runtime.h>

#define B_SZ   16384
#define F_N    26
#define V_N    100000
#define D_N    64
#define H1_N   512
#define H2_N   256
#define IN_DIM 1989
#define KPAD   2048

typedef _Float16 half8_t __attribute__((ext_vector_type(8)));
typedef _Float16 half4_t __attribute__((ext_vector_type(4)));
typedef float    floatx4 __attribute__((ext_vector_type(4)));

#define MFMA16(a, b, c) __builtin_amdgcn_mfma_f32_16x16x32_f16((a), (b), (c), 0, 0, 0)

__device__ __forceinline__ void load_lds16(const void* g, void* l) {
    __builtin_amdgcn_global_load_lds(
        (const __attribute__((address_space(1))) unsigned int*)g,
        (__attribute__((address_space(3))) unsigned int*)l,
        16, 0, 0);
}

// ---------------------------------------------------------------------------
// Weight prep: WT[n][k] = fp16(W[k][n]), zero pad k in [K, Kpad)
// Consecutive threads -> consecutive n: coalesced read; 2B writes merge in L2.
// ---------------------------------------------------------------------------
__global__ __launch_bounds__(256) void prep_w(const float* __restrict__ W,
                                              _Float16* __restrict__ WT,
                                              int K, int N, int Kpad) {
    int t = blockIdx.x * 256 + threadIdx.x;
    if (t >= N * Kpad) return;
    int k = t / N;            // N is a power of two here (512 / 256)
    int n = t - k * N;
    WT[(size_t)n * Kpad + k] = (k < K) ? (_Float16)W[(size_t)k * N + n] : (_Float16)0.f;
}

// ---------------------------------------------------------------------------
// Gather + interactions. 4 samples per block (one per wave).
// joint row: [0,1664) = emb flat (fp16), [1664,1989) = upper-tri gram, pad->0
// ---------------------------------------------------------------------------
#define EMB_STRIDE 72                      // 64 + 8 pad halfs (breaks bank alias)
#define EMB_PER_SAMPLE (32 * EMB_STRIDE)   // 32 rows (26 data + 6 zero)

__global__ __launch_bounds__(256) void gather_interact(
        const int* __restrict__ idx,
        const float* __restrict__ tables,
        _Float16* __restrict__ joint) {
    __shared__ __align__(16) _Float16 embh[4 * EMB_PER_SAMPLE];
    __shared__ int sidx[4 * F_N];
    const int tid = threadIdx.x;
    const int b0  = blockIdx.x * 4;

    if (tid < 4 * F_N) sidx[tid] = idx[(size_t)b0 * F_N + tid];

    // zero MFMA pad rows 26..31 (k in [0,64))
    for (int z = tid; z < 4 * 6 * 16; z += 256) {
        int s = z / 96, rem = z % 96;
        int f = F_N + rem / 16, d4 = (rem % 16) * 4;
        half4_t zz; zz[0] = 0; zz[1] = 0; zz[2] = 0; zz[3] = 0;
        *(half4_t*)(embh + s * EMB_PER_SAMPLE + f * EMB_STRIDE + d4) = zz;
    }
    __syncthreads();

    // gather: 4 samples x 26 rows x 16 float4 chunks = 1664 chunks
    // phase (a): issue all independent loads; phase (b): convert + store
    float4 v[7];
    #pragma unroll
    for (int i = 0; i < 7; ++i) {
        int c = tid + i * 256;
        if (c < 4 * F_N * 16) {
            int s = c / 416, rem = c - s * 416;
            int f = rem >> 4, d4 = (rem & 15) * 4;
            v[i] = *(const float4*)(tables +
                     ((size_t)f * V_N + sidx[s * F_N + f]) * D_N + d4);
        }
    }
    #pragma unroll
    for (int i = 0; i < 7; ++i) {
        int c = tid + i * 256;
        if (c < 4 * F_N * 16) {
            int s = c / 416, rem = c - s * 416;
            int f = rem >> 4, d4 = (rem & 15) * 4;
            half4_t h;
            h[0] = (_Float16)v[i].x; h[1] = (_Float16)v[i].y;
            h[2] = (_Float16)v[i].z; h[3] = (_Float16)v[i].w;
            *(half4_t*)(embh + s * EMB_PER_SAMPLE + f * EMB_STRIDE + d4) = h;
            *(half4_t*)(joint + (size_t)(b0 + s) * KPAD + f * D_N + d4) = h;
        }
    }
    // zero joint K-pad
    for (int q = tid; q < 4 * (KPAD - IN_DIM); q += 256) {
        int s = q / (KPAD - IN_DIM), p = q % (KPAD - IN_DIM);
        joint[(size_t)(b0 + s) * KPAD + IN_DIM + p] = (_Float16)0.f;
    }
    __syncthreads();

    // per-wave gram via MFMA: gram = E (32x64) x E^T (64x32), E^T B-frag == E A-frag
    const int wave = tid >> 6, lane = tid & 63;
    const _Float16* eb = embh + wave * EMB_PER_SAMPLE;
    const int fr = lane & 15;
    const int fk = (lane >> 4) * 8;
    floatx4 a00 = {0.f, 0.f, 0.f, 0.f};
    floatx4 a01 = {0.f, 0.f, 0.f, 0.f};
    floatx4 a11 = {0.f, 0.f, 0.f, 0.f};
    #pragma unroll
    for (int k0 = 0; k0 < 64; k0 += 32) {
        half8_t f0 = *(const half8_t*)(eb + fr * EMB_STRIDE + k0 + fk);
        half8_t f1 = *(const half8_t*)(eb + (16 + fr) * EMB_STRIDE + k0 + fk);
        a00 = MFMA16(f0, f0, a00);   // m in [0,16),  n in [0,16)
        a01 = MFMA16(f0, f1, a01);   // m in [0,16),  n in [16,32)
        a11 = MFMA16(f1, f1, a11);   // m in [16,32), n in [16,32)
    }
    // extract upper triangle: D[row=(lane>>4)*4+r][col=lane&15]
    _Float16* jrow = joint + (size_t)(b0 + wave) * KPAD + F_N * D_N;
    #pragma unroll
    for (int r = 0; r < 4; ++r) {
        int mb = (lane >> 4) * 4 + r;
        {   // tile (0,0): m=mb, n=fr
            int m = mb, n = fr;
            if (m < n) jrow[(m * (51 - m)) / 2 + n - m - 1] = (_Float16)a00[r];
        }
        {   // tile (0,1): m=mb, n=16+fr
            int m = mb, n = 16 + fr;
            if (n < F_N) jrow[(m * (51 - m)) / 2 + n - m - 1] = (_Float16)a01[r];
        }
        {   // tile (1,1): m=16+mb, n=16+fr
            int m = 16 + mb, n = 16 + fr;
            if (m < n && n < F_N) jrow[(m * (51 - m)) / 2 + n - m - 1] = (_Float16)a11[r];
        }
    }
}

// ---------------------------------------------------------------------------
// C = relu(A @ Bt^T + bias), fp16 in/out, fp32 accumulate.
// 128x128 tile, BK=32, 256 threads (4 waves, each 64x64).
// NEW: T3-minimum 2-phase double-buffer — STAGE(next buf) is issued BEFORE
// compute(cur buf); ONE __syncthreads per K-step (its vmcnt(0)+lgkmcnt(0)
// drain is exactly the required wait). Loads fly during MFMA instead of
// being serialized against it — critical at this grid's 2 blocks/CU.
// ---------------------------------------------------------------------------
__global__ __launch_bounds__(256) void gemm_bt(
        const _Float16* __restrict__ A, int lda,
        const _Float16* __restrict__ Bt, int ldb,
        const float* __restrict__ bias,
        _Float16* __restrict__ C, int ldc,
        int K, int nblocks) {
    __shared__ __align__(16) _Float16 As[2][128 * 32];   // 8 KB per buf
    __shared__ __align__(16) _Float16 Bs[2][128 * 32];
    const int tid  = threadIdx.x;
    const int wave = tid >> 6;
    const int lane = tid & 63;
    int bid = blockIdx.x;
    if ((gridDim.x & 7) == 0) {             // bijective chunked XCD swizzle
        const int cpx = gridDim.x >> 3;
        bid = (bid & 7) * cpx + (bid >> 3);
    }
    const int bm = bid / nblocks;
    const int bn = bid % nblocks;
    const int m0 = bm * 128, n0 = bn * 128;

    // staging: 512 chunks of 16B per tile; chunk c -> row c>>2, k-part (c&3)*8
    const int c0 = tid, c1 = tid + 256;
    const _Float16* ag0 = A  + (size_t)(m0 + (c0 >> 2)) * lda + (c0 & 3) * 8;
    const _Float16* ag1 = A  + (size_t)(m0 + (c1 >> 2)) * lda + (c1 & 3) * 8;
    const _Float16* bg0 = Bt + (size_t)(n0 + (c0 >> 2)) * ldb + (c0 & 3) * 8;
    const _Float16* bg1 = Bt + (size_t)(n0 + (c1 >> 2)) * ldb + (c1 & 3) * 8;

    floatx4 acc[4][4];
    #pragma unroll
    for (int i = 0; i < 4; ++i)
        #pragma unroll
        for (int j = 0; j < 4; ++j) acc[i][j] = (floatx4){0.f, 0.f, 0.f, 0.f};

    const int wm = (wave >> 1) * 64;
    const int wn = (wave & 1) * 64;
    const int fr = lane & 15;
    const int fk = (lane >> 4) * 8;

    auto stage = [&](int buf, int k0) {
        char* ab = (char*)As + buf * 8192;
        char* bb = (char*)Bs + buf * 8192;
        load_lds16(ag0 + k0, ab + wave * 1024);
        load_lds16(ag1 + k0, ab + 4096 + wave * 1024);
        load_lds16(bg0 + k0, bb + wave * 1024);
        load_lds16(bg1 + k0, bb + 4096 + wave * 1024);
    };
    auto compute = [&](int buf) {
        const _Float16* as = &As[buf][0];
        const _Float16* bs = &Bs[buf][0];
        half8_t af[4], bf[4];
        #pragma unroll
        for (int i = 0; i < 4; ++i)
            af[i] = *(const half8_t*)(as + (wm + i * 16 + fr) * 32 + fk);
        #pragma unroll
        for (int j = 0; j < 4; ++j)
            bf[j] = *(const half8_t*)(bs + (wn + j * 16 + fr) * 32 + fk);
        #pragma unroll
        for (int i = 0; i < 4; ++i)
            #pragma unroll
            for (int j = 0; j < 4; ++j)
                acc[i][j] = MFMA16(af[i], bf[j], acc[i][j]);
    };

    stage(0, 0);
    __syncthreads();                       // drain prologue loads
    int cur = 0;
    for (int k0 = 32; k0 < K; k0 += 32) {
        stage(cur ^ 1, k0);                // next tile's loads in flight...
        compute(cur);                      // ...under this tile's compute
        __syncthreads();                   // vmcnt(0)+lgkmcnt(0)+barrier
        cur ^= 1;
    }
    compute(cur);                          // last tile, no prefetch

    const int colb = n0 + wn + fr;
    const int rowb = m0 + wm + (lane >> 4) * 4;
    #pragma unroll
    for (int j = 0; j < 4; ++j) {
        const int c = colb + j * 16;
        const float bv = bias[c];
        #pragma unroll
        for (int i = 0; i < 4; ++i)
            #pragma unroll
            for (int r = 0; r < 4; ++r) {
                float v = acc[i][j][r] + bv;
                v = fmaxf(v, 0.f);
                C[(size_t)(rowb + i * 16 + r) * ldc + c] = (_Float16)v;
            }
    }
}

// ---------------------------------------------------------------------------
// Fused tail: out = relu(h1 @ W2 + b2) @ W3 + b3.
// Re-tiled: 64 rows x 256 cols per block, 256 threads (4 waves, each 64x64
// in n), grid 256 -> full GPU (was 128 blocks = half idle). Same 2-phase
// double-buffer as gemm_bt. h2 never leaves registers.
// ---------------------------------------------------------------------------
__global__ __launch_bounds__(256) void fused_tail(
        const _Float16* __restrict__ h1, const _Float16* __restrict__ W2T,
        const float* __restrict__ b2, const float* __restrict__ W3,
        const float* __restrict__ b3, float* __restrict__ out) {
    __shared__ __align__(16) _Float16 As[2][64 * 32];    // 4 KB per buf
    __shared__ __align__(16) _Float16 Bs[2][256 * 32];   // 16 KB per buf
    __shared__ float red[4][64];
    const int tid  = threadIdx.x;
    const int wave = tid >> 6;
    const int lane = tid & 63;
    const int m0 = blockIdx.x * 64;

    // A: 64x32 = 256 chunks (1/thread); B: 256x32 = 1024 chunks (4/thread)
    const _Float16* ag  = h1  + (size_t)(m0 + (tid >> 2)) * H1_N + (tid & 3) * 8;
    const _Float16* bg0 = W2T + (size_t)(tid >> 2) * H1_N + (tid & 3) * 8;

    floatx4 acc[4][4];
    #pragma unroll
    for (int i = 0; i < 4; ++i)
        #pragma unroll
        for (int j = 0; j < 4; ++j) acc[i][j] = (floatx4){0.f, 0.f, 0.f, 0.f};

    const int wn = wave * 64;
    const int fr = lane & 15;
    const int fk = (lane >> 4) * 8;

    auto stage = [&](int buf, int k0) {
        char* ab = (char*)As + buf * 4096;
        char* bb = (char*)Bs + buf * 16384;
        load_lds16(ag + k0, ab + wave * 1024);
        #pragma unroll
        for (int i = 0; i < 4; ++i)
            load_lds16(bg0 + (size_t)i * 64 * H1_N + k0,
                       bb + i * 4096 + wave * 1024);
    };
    auto compute = [&](int buf) {
        const _Float16* as = &As[buf][0];
        const _Float16* bs = &Bs[buf][0];
        half8_t af[4], bf[4];
        #pragma unroll
        for (int i = 0; i < 4; ++i)
            af[i] = *(const half8_t*)(as + (i * 16 + fr) * 32 + fk);
        #pragma unroll
        for (int j = 0; j < 4; ++j)
            bf[j] = *(const half8_t*)(bs + (wn + j * 16 + fr) * 32 + fk);
        #pragma unroll
        for (int i = 0; i < 4; ++i)
            #pragma unroll
            for (int j = 0; j < 4; ++j)
                acc[i][j] = MFMA16(af[i], bf[j], acc[i][j]);
    };

    stage(0, 0);
    __syncthreads();
    int cur = 0;
    for (int k0 = 32; k0 < H1_N; k0 += 32) {
        stage(cur ^ 1, k0);
        compute(cur);
        __syncthreads();
        cur ^= 1;
    }
    compute(cur);

    // epilogue: h2 = relu(acc + b2[col]); p = h2 . W3 over this wave's 64 cols
    float b2v[4], w3v[4];
    #pragma unroll
    for (int j = 0; j < 4; ++j) {
        const int c = wn + j * 16 + fr;
        b2v[j] = b2[c];
        w3v[j] = W3[c];
    }
    #pragma unroll
    for (int i = 0; i < 4; ++i)
        #pragma unroll
        for (int r = 0; r < 4; ++r) {
            float p = 0.f;
            #pragma unroll
            for (int j = 0; j < 4; ++j) {
                float h = acc[i][j][r] + b2v[j];
                h = fmaxf(h, 0.f);
                p += h * w3v[j];
            }
            p += __shfl_xor(p, 1, 16);
            p += __shfl_xor(p, 2, 16);
            p += __shfl_xor(p, 4, 16);
            p += __shfl_xor(p, 8, 16);
            if (fr == 0)
                red[wave][i * 16 + (lane >> 4) * 4 + r] = p;
        }
    __syncthreads();
    if (tid < 64) {
        float s = red[0][tid] + red[1][tid] + red[2][tid] + red[3][tid] + b3[0];
        out[m0 + tid] = s;
    }
}

// ---------------------------------------------------------------------------
extern "C" void kernel_launch(void* const* d_in, const int* in_sizes, int n_in,
                              void* d_out, int out_size, void* d_ws, size_t ws_size,
                              hipStream_t stream) {
    const int*   idx    = (const int*)d_in[0];
    const float* tables = (const float*)d_in[1];
    const float* W1     = (const float*)d_in[2];
    const float* b1     = (const float*)d_in[3];
    const float* W2     = (const float*)d_in[4];
    const float* b2     = (const float*)d_in[5];
    const float* W3     = (const float*)d_in[6];
    const float* b3     = (const float*)d_in[7];
    float* out = (float*)d_out;

    char* ws = (char*)d_ws;
    // joint: 16384*2048*2      =  67,108,864
    // W1T:   512*2048*2        =   2,097,152
    // h1:    16384*512*2       =  16,777,216
    // W2T:   256*512*2         =     262,144   total ~86.2 MB
    _Float16* joint = (_Float16*)(ws);
    _Float16* W1T   = (_Float16*)(ws + 67108864);
    _Float16* h1    = (_Float16*)(ws + 69206016);
    _Float16* W2T   = (_Float16*)(ws + 85983232);

    prep_w<<<(H1_N * KPAD + 255) / 256, 256, 0, stream>>>(W1, W1T, IN_DIM, H1_N, KPAD);
    prep_w<<<(H2_N * H1_N + 255) / 256, 256, 0, stream>>>(W2, W2T, H1_N, H2_N, H1_N);
    gather_interact<<<B_SZ / 4, 256, 0, stream>>>(idx, tables, joint);
    gemm_bt<<<(B_SZ / 128) * (H1_N / 128), 256, 0, stream>>>(
        joint, KPAD, W1T, KPAD, b1, h1, H1_N, KPAD, H1_N / 128);
    fused_tail<<<B_SZ / 64, 256, 0, stream>>>(h1, W2T, b2, W3, b3, out);
}

// Round 3
// 814.428 us; speedup vs baseline: 1.0261x; 1.0127x over previous
//
#include <hip/hip_runtime.h>

#define B_SZ   16384
#define F_N    26
#define V_N    100000
#define D_N    64
#define H1_N   512
#define H2_N   256
#define IN_DIM 1989
#define KPAD   2048

typedef _Float16 half8_t __attribute__((ext_vector_type(8)));
typedef _Float16 half4_t __attribute__((ext_vector_type(4)));
typedef float    floatx4 __attribute__((ext_vector_type(4)));

#define MFMA16(a, b, c) __builtin_amdgcn_mfma_f32_16x16x32_f16((a), (b), (c), 0, 0, 0)

__device__ __forceinline__ void load_lds16(const void* g, void* l) {
    __builtin_amdgcn_global_load_lds(
        (const __attribute__((address_space(1))) unsigned int*)g,
        (__attribute__((address_space(3))) unsigned int*)l,
        16, 0, 0);
}

// ---------------------------------------------------------------------------
// Gather + interactions + (folded) weight prep. 4 samples per block.
// The 4096x256 threads of this grid exactly cover W1T's 512*2048 elements
// (1 per thread) and the first 512 blocks cover W2T's 256*512 — removes the
// two prep_w launches and their serialization bubbles.
// joint row: [0,1664) = emb flat (fp16), [1664,1989) = upper-tri gram, pad->0
// ---------------------------------------------------------------------------
#define EMB_STRIDE 72                      // 64 + 8 pad halfs (breaks bank alias)
#define EMB_PER_SAMPLE (32 * EMB_STRIDE)   // 32 rows (26 data + 6 zero)

__global__ __launch_bounds__(256) void gather_interact(
        const int* __restrict__ idx,
        const float* __restrict__ tables,
        _Float16* __restrict__ joint,
        const float* __restrict__ W1,
        const float* __restrict__ W2,
        _Float16* __restrict__ W1T,
        _Float16* __restrict__ W2T) {
    __shared__ __align__(16) _Float16 embh[4 * EMB_PER_SAMPLE];
    __shared__ int sidx[4 * F_N];
    const int tid = threadIdx.x;
    const int b0  = blockIdx.x * 4;

    // folded weight prep (independent of the rest; coalesced reads,
    // 2B scattered writes merge in L2 since every WT line is fully written)
    {
        int t = blockIdx.x * 256 + tid;            // [0, 1048576) == 512*2048
        int k = t >> 9, n = t & 511;
        W1T[(size_t)n * KPAD + k] =
            (k < IN_DIM) ? (_Float16)W1[(size_t)k * H1_N + n] : (_Float16)0.f;
        if (blockIdx.x < 512) {                    // [0, 131072) == 256*512
            int k2 = t >> 8, n2 = t & 255;
            W2T[(size_t)n2 * H1_N + k2] = (_Float16)W2[(size_t)k2 * H2_N + n2];
        }
    }

    if (tid < 4 * F_N) sidx[tid] = idx[(size_t)b0 * F_N + tid];

    // zero MFMA pad rows 26..31 (k in [0,64))
    for (int z = tid; z < 4 * 6 * 16; z += 256) {
        int s = z / 96, rem = z % 96;
        int f = F_N + rem / 16, d4 = (rem % 16) * 4;
        half4_t zz; zz[0] = 0; zz[1] = 0; zz[2] = 0; zz[3] = 0;
        *(half4_t*)(embh + s * EMB_PER_SAMPLE + f * EMB_STRIDE + d4) = zz;
    }
    __syncthreads();

    // gather: 4 samples x 26 rows x 16 float4 chunks = 1664 chunks
    // phase (a): issue all independent loads; phase (b): convert + store
    float4 v[7];
    #pragma unroll
    for (int i = 0; i < 7; ++i) {
        int c = tid + i * 256;
        if (c < 4 * F_N * 16) {
            int s = c / 416, rem = c - s * 416;
            int f = rem >> 4, d4 = (rem & 15) * 4;
            v[i] = *(const float4*)(tables +
                     ((size_t)f * V_N + sidx[s * F_N + f]) * D_N + d4);
        }
    }
    #pragma unroll
    for (int i = 0; i < 7; ++i) {
        int c = tid + i * 256;
        if (c < 4 * F_N * 16) {
            int s = c / 416, rem = c - s * 416;
            int f = rem >> 4, d4 = (rem & 15) * 4;
            half4_t h;
            h[0] = (_Float16)v[i].x; h[1] = (_Float16)v[i].y;
            h[2] = (_Float16)v[i].z; h[3] = (_Float16)v[i].w;
            *(half4_t*)(embh + s * EMB_PER_SAMPLE + f * EMB_STRIDE + d4) = h;
            *(half4_t*)(joint + (size_t)(b0 + s) * KPAD + f * D_N + d4) = h;
        }
    }
    // zero joint K-pad
    for (int q = tid; q < 4 * (KPAD - IN_DIM); q += 256) {
        int s = q / (KPAD - IN_DIM), p = q % (KPAD - IN_DIM);
        joint[(size_t)(b0 + s) * KPAD + IN_DIM + p] = (_Float16)0.f;
    }
    __syncthreads();

    // per-wave gram via MFMA: gram = E (32x64) x E^T (64x32), E^T B-frag == E A-frag
    const int wave = tid >> 6, lane = tid & 63;
    const _Float16* eb = embh + wave * EMB_PER_SAMPLE;
    const int fr = lane & 15;
    const int fk = (lane >> 4) * 8;
    floatx4 a00 = {0.f, 0.f, 0.f, 0.f};
    floatx4 a01 = {0.f, 0.f, 0.f, 0.f};
    floatx4 a11 = {0.f, 0.f, 0.f, 0.f};
    #pragma unroll
    for (int k0 = 0; k0 < 64; k0 += 32) {
        half8_t f0 = *(const half8_t*)(eb + fr * EMB_STRIDE + k0 + fk);
        half8_t f1 = *(const half8_t*)(eb + (16 + fr) * EMB_STRIDE + k0 + fk);
        a00 = MFMA16(f0, f0, a00);   // m in [0,16),  n in [0,16)
        a01 = MFMA16(f0, f1, a01);   // m in [0,16),  n in [16,32)
        a11 = MFMA16(f1, f1, a11);   // m in [16,32), n in [16,32)
    }
    // extract upper triangle: D[row=(lane>>4)*4+r][col=lane&15]
    _Float16* jrow = joint + (size_t)(b0 + wave) * KPAD + F_N * D_N;
    #pragma unroll
    for (int r = 0; r < 4; ++r) {
        int mb = (lane >> 4) * 4 + r;
        {   // tile (0,0): m=mb, n=fr
            int m = mb, n = fr;
            if (m < n) jrow[(m * (51 - m)) / 2 + n - m - 1] = (_Float16)a00[r];
        }
        {   // tile (0,1): m=mb, n=16+fr
            int m = mb, n = 16 + fr;
            if (n < F_N) jrow[(m * (51 - m)) / 2 + n - m - 1] = (_Float16)a01[r];
        }
        {   // tile (1,1): m=16+mb, n=16+fr
            int m = 16 + mb, n = 16 + fr;
            if (m < n && n < F_N) jrow[(m * (51 - m)) / 2 + n - m - 1] = (_Float16)a11[r];
        }
    }
}

// ---------------------------------------------------------------------------
// C = relu(A @ Bt^T + bias), fp16 in/out, fp32 accumulate.
// 128x128 tile, BK=32, 256 threads (4 waves, each 64x64).
// NEW: T4 depth-2 counted-vmcnt pipeline (m139/m218 pattern), 3 LDS buffers.
// Stages for k+1 AND k+2 stay in flight across a raw s_barrier; each iter
// waits only vmcnt(4) (= the oldest stage's 4 global_load_lds), never
// draining the prefetch queue. Load latency now spans TWO compute phases —
// the lever for this grid's 2 blocks/CU.
// Wait correctness (vmcnt retires in issue order, m135): at iter i the
// outstanding loads are stage(i) [oldest, 4] + stage(i+1) [4]; vmcnt(4)
// retires exactly stage(i). Last iter (no stage issued) uses vmcnt(0).
// ---------------------------------------------------------------------------
__global__ __launch_bounds__(256) void gemm_bt(
        const _Float16* __restrict__ A, int lda,
        const _Float16* __restrict__ Bt, int ldb,
        const float* __restrict__ bias,
        _Float16* __restrict__ C, int ldc,
        int K, int nblocks) {
    __shared__ __align__(16) _Float16 As[3][128 * 32];   // 8 KB per buf
    __shared__ __align__(16) _Float16 Bs[3][128 * 32];
    const int tid  = threadIdx.x;
    const int wave = tid >> 6;
    const int lane = tid & 63;
    int bid = blockIdx.x;
    if ((gridDim.x & 7) == 0) {             // bijective chunked XCD swizzle
        const int cpx = gridDim.x >> 3;
        bid = (bid & 7) * cpx + (bid >> 3);
    }
    const int bm = bid / nblocks;
    const int bn = bid % nblocks;
    const int m0 = bm * 128, n0 = bn * 128;

    // staging: 512 chunks of 16B per tile; chunk c -> row c>>2, k-part (c&3)*8
    const int c0 = tid, c1 = tid + 256;
    const _Float16* ag0 = A  + (size_t)(m0 + (c0 >> 2)) * lda + (c0 & 3) * 8;
    const _Float16* ag1 = A  + (size_t)(m0 + (c1 >> 2)) * lda + (c1 & 3) * 8;
    const _Float16* bg0 = Bt + (size_t)(n0 + (c0 >> 2)) * ldb + (c0 & 3) * 8;
    const _Float16* bg1 = Bt + (size_t)(n0 + (c1 >> 2)) * ldb + (c1 & 3) * 8;

    floatx4 acc[4][4];
    #pragma unroll
    for (int i = 0; i < 4; ++i)
        #pragma unroll
        for (int j = 0; j < 4; ++j) acc[i][j] = (floatx4){0.f, 0.f, 0.f, 0.f};

    const int wm = (wave >> 1) * 64;
    const int wn = (wave & 1) * 64;
    const int fr = lane & 15;
    const int fk = (lane >> 4) * 8;

    auto stage = [&](int buf, int k0) {
        char* ab = (char*)As + buf * 8192;
        char* bb = (char*)Bs + buf * 8192;
        load_lds16(ag0 + k0, ab + wave * 1024);
        load_lds16(ag1 + k0, ab + 4096 + wave * 1024);
        load_lds16(bg0 + k0, bb + wave * 1024);
        load_lds16(bg1 + k0, bb + 4096 + wave * 1024);
    };
    auto compute = [&](int buf) {
        const _Float16* as = &As[buf][0];
        const _Float16* bs = &Bs[buf][0];
        half8_t af[4], bf[4];
        #pragma unroll
        for (int i = 0; i < 4; ++i)
            af[i] = *(const half8_t*)(as + (wm + i * 16 + fr) * 32 + fk);
        #pragma unroll
        for (int j = 0; j < 4; ++j)
            bf[j] = *(const half8_t*)(bs + (wn + j * 16 + fr) * 32 + fk);
        #pragma unroll
        for (int i = 0; i < 4; ++i)
            #pragma unroll
            for (int j = 0; j < 4; ++j)
                acc[i][j] = MFMA16(af[i], bf[j], acc[i][j]);
    };

    const int nsteps = K >> 5;             // 64 for K=2048
    stage(0, 0);
    stage(1, 32);
    int i = 0;
    for (; i < nsteps - 1; ++i) {
        // wait ONLY the oldest stage (i); stage(i+1) stays in flight
        asm volatile("s_waitcnt vmcnt(4)" ::: "memory");
        __builtin_amdgcn_s_barrier();      // all waves' stage(i) now landed;
                                           // all reads of buf (i+2)%3 done
        if (i + 2 < nsteps) stage((i + 2) % 3, (i + 2) * 32);
        compute(i % 3);
    }
    asm volatile("s_waitcnt vmcnt(0)" ::: "memory");
    __builtin_amdgcn_s_barrier();
    compute(i % 3);

    const int colb = n0 + wn + fr;
    const int rowb = m0 + wm + (lane >> 4) * 4;
    #pragma unroll
    for (int j = 0; j < 4; ++j) {
        const int c = colb + j * 16;
        const float bv = bias[c];
        #pragma unroll
        for (int i2 = 0; i2 < 4; ++i2)
            #pragma unroll
            for (int r = 0; r < 4; ++r) {
                float v = acc[i2][j][r] + bv;
                v = fmaxf(v, 0.f);
                C[(size_t)(rowb + i2 * 16 + r) * ldc + c] = (_Float16)v;
            }
    }
}

// ---------------------------------------------------------------------------
// Fused tail: out = relu(h1 @ W2 + b2) @ W3 + b3.
// 64 rows x 256 cols per block, 256 threads (4 waves, each 64x64 in n),
// grid 256 -> full GPU. 2-phase double-buffer. h2 never leaves registers.
// (Kept stable this round — one risky kernel per round.)
// ---------------------------------------------------------------------------
__global__ __launch_bounds__(256) void fused_tail(
        const _Float16* __restrict__ h1, const _Float16* __restrict__ W2T,
        const float* __restrict__ b2, const float* __restrict__ W3,
        const float* __restrict__ b3, float* __restrict__ out) {
    __shared__ __align__(16) _Float16 As[2][64 * 32];    // 4 KB per buf
    __shared__ __align__(16) _Float16 Bs[2][256 * 32];   // 16 KB per buf
    __shared__ float red[4][64];
    const int tid  = threadIdx.x;
    const int wave = tid >> 6;
    const int lane = tid & 63;
    const int m0 = blockIdx.x * 64;

    // A: 64x32 = 256 chunks (1/thread); B: 256x32 = 1024 chunks (4/thread)
    const _Float16* ag  = h1  + (size_t)(m0 + (tid >> 2)) * H1_N + (tid & 3) * 8;
    const _Float16* bg0 = W2T + (size_t)(tid >> 2) * H1_N + (tid & 3) * 8;

    floatx4 acc[4][4];
    #pragma unroll
    for (int i = 0; i < 4; ++i)
        #pragma unroll
        for (int j = 0; j < 4; ++j) acc[i][j] = (floatx4){0.f, 0.f, 0.f, 0.f};

    const int wn = wave * 64;
    const int fr = lane & 15;
    const int fk = (lane >> 4) * 8;

    auto stage = [&](int buf, int k0) {
        char* ab = (char*)As + buf * 4096;
        char* bb = (char*)Bs + buf * 16384;
        load_lds16(ag + k0, ab + wave * 1024);
        #pragma unroll
        for (int i = 0; i < 4; ++i)
            load_lds16(bg0 + (size_t)i * 64 * H1_N + k0,
                       bb + i * 4096 + wave * 1024);
    };
    auto compute = [&](int buf) {
        const _Float16* as = &As[buf][0];
        const _Float16* bs = &Bs[buf][0];
        half8_t af[4], bf[4];
        #pragma unroll
        for (int i = 0; i < 4; ++i)
            af[i] = *(const half8_t*)(as + (i * 16 + fr) * 32 + fk);
        #pragma unroll
        for (int j = 0; j < 4; ++j)
            bf[j] = *(const half8_t*)(bs + (wn + j * 16 + fr) * 32 + fk);
        #pragma unroll
        for (int i = 0; i < 4; ++i)
            #pragma unroll
            for (int j = 0; j < 4; ++j)
                acc[i][j] = MFMA16(af[i], bf[j], acc[i][j]);
    };

    stage(0, 0);
    __syncthreads();
    int cur = 0;
    for (int k0 = 32; k0 < H1_N; k0 += 32) {
        stage(cur ^ 1, k0);
        compute(cur);
        __syncthreads();
        cur ^= 1;
    }
    compute(cur);

    // epilogue: h2 = relu(acc + b2[col]); p = h2 . W3 over this wave's 64 cols
    float b2v[4], w3v[4];
    #pragma unroll
    for (int j = 0; j < 4; ++j) {
        const int c = wn + j * 16 + fr;
        b2v[j] = b2[c];
        w3v[j] = W3[c];
    }
    #pragma unroll
    for (int i = 0; i < 4; ++i)
        #pragma unroll
        for (int r = 0; r < 4; ++r) {
            float p = 0.f;
            #pragma unroll
            for (int j = 0; j < 4; ++j) {
                float h = acc[i][j][r] + b2v[j];
                h = fmaxf(h, 0.f);
                p += h * w3v[j];
            }
            p += __shfl_xor(p, 1, 16);
            p += __shfl_xor(p, 2, 16);
            p += __shfl_xor(p, 4, 16);
            p += __shfl_xor(p, 8, 16);
            if (fr == 0)
                red[wave][i * 16 + (lane >> 4) * 4 + r] = p;
        }
    __syncthreads();
    if (tid < 64) {
        float s = red[0][tid] + red[1][tid] + red[2][tid] + red[3][tid] + b3[0];
        out[m0 + tid] = s;
    }
}

// ---------------------------------------------------------------------------
extern "C" void kernel_launch(void* const* d_in, const int* in_sizes, int n_in,
                              void* d_out, int out_size, void* d_ws, size_t ws_size,
                              hipStream_t stream) {
    const int*   idx    = (const int*)d_in[0];
    const float* tables = (const float*)d_in[1];
    const float* W1     = (const float*)d_in[2];
    const float* b1     = (const float*)d_in[3];
    const float* W2     = (const float*)d_in[4];
    const float* b2     = (const float*)d_in[5];
    const float* W3     = (const float*)d_in[6];
    const float* b3     = (const float*)d_in[7];
    float* out = (float*)d_out;

    char* ws = (char*)d_ws;
    // joint: 16384*2048*2      =  67,108,864
    // W1T:   512*2048*2        =   2,097,152
    // h1:    16384*512*2       =  16,777,216
    // W2T:   256*512*2         =     262,144   total ~86.2 MB
    _Float16* joint = (_Float16*)(ws);
    _Float16* W1T   = (_Float16*)(ws + 67108864);
    _Float16* h1    = (_Float16*)(ws + 69206016);
    _Float16* W2T   = (_Float16*)(ws + 85983232);

    gather_interact<<<B_SZ / 4, 256, 0, stream>>>(idx, tables, joint,
                                                  W1, W2, W1T, W2T);
    gemm_bt<<<(B_SZ / 128) * (H1_N / 128), 256, 0, stream>>>(
        joint, KPAD, W1T, KPAD, b1, h1, H1_N, KPAD, H1_N / 128);
    fused_tail<<<B_SZ / 64, 256, 0, stream>>>(h1, W2T, b2, W3, b3, out);
}